// Round 9
// baseline (1849.508 us; speedup 1.0000x reference)
//
#include <hip/hip_runtime.h>
#include <hip/hip_cooperative_groups.h>

namespace cg = cooperative_groups;

// Point-splat renderer, round 9: ONE cooperative kernel for all passes.
//
// Structure: [fill dispatch] -> [cooperative fused kernel] .
//  - fill is a separate dispatch so its plain uint4 stores are flushed from
//    L2 (dispatch-end release) before any memory-side atomicMax can race a
//    dirty winner line (lost-update hazard inside a single kernel).
//  - fused kernel: 10 descending-index chunk passes. Pass k: project chunk
//    [b[k+1],b[k]) skipping pixels whose bit is set in mask_read (built in
//    phase k-1), then build mask_write with bit p = (winner[p] >= b[k+1]);
//    then __threadfence(); grid.sync().
//    Race/staleness safety: any mask bit ever observed is a TRUE
//    "winner >= thresh" certificate (thresholds only decrease across passes,
//    winner only grows; stale L2 copies are older=stronger masks) -> wrong
//    skips impossible, missing bits just cost extra atomics. winner is
//    written ONLY by device-scope (memory-side) atomics after the fill
//    dispatch, so no plain dirty lines can overwrite an atomic result.
//    fence-before-sync = writers write back dirty mask lines + own L2 is
//    invalidated with no touches until after the barrier -> post-sync reads
//    fetch fresh memory-side data.
//  - paint fused as the final phase.
//
// Inputs: d_in[0] positions (N*3 f32), d_in[1] colors (N*3 f32),
//         d_in[2] camera_pose (16 f32), d_in[3] intrinsics (9 f32),
//         d_in[4] H (1 int), d_in[5] W (1 int)
// Output: (1,3,H,W) f32 flat.

#define BLOCK 256
#define COOP_BLOCKS 1024   // 4 blocks/CU on 256 CUs: co-residency guaranteed
#define NP 10

__global__ void fill_ff_kernel(uint4* __restrict__ p, int n4) {
    int i = blockIdx.x * blockDim.x + threadIdx.x;
    uint4 v = make_uint4(~0u, ~0u, ~0u, ~0u);
    for (; i < n4; i += gridDim.x * blockDim.x) p[i] = v;
}

__global__ void __launch_bounds__(BLOCK)
fused_kernel(const float* __restrict__ pos,
             const float* __restrict__ colors,
             const float* __restrict__ pose,
             const float* __restrict__ intr,
             const int* __restrict__ Hp,
             const int* __restrict__ Wp,
             int* __restrict__ winner,
             unsigned* __restrict__ maskA,
             unsigned* __restrict__ maskB,
             float* __restrict__ out,
             int n, int HW) {
    cg::grid_group grid = cg::this_grid();
    int tid = blockIdx.x * blockDim.x + threadIdx.x;
    int nth = gridDim.x * blockDim.x;

    float r00 = pose[0], r01 = pose[1], r02 = pose[2],  t0 = pose[3];
    float r10 = pose[4], r11 = pose[5], r12 = pose[6],  t1 = pose[7];
    float r20 = pose[8], r21 = pose[9], r22 = pose[10], t2 = pose[11];
    float fx = intr[0], cx = intr[2];
    float fy = intr[4], cy = intr[5];
    int W = *Wp, H = *Hp;

    // Descending chunk bounds, in 64ths of n: sizes 1,1,2,2,4,4,8,8,14,20.
    const int frac[NP + 1] = {64, 63, 62, 60, 58, 54, 50, 42, 34, 20, 0};
    long long ln = n;

    for (int k = 0; k < NP; ++k) {
        int end   = (int)(ln * frac[k]     / 64);
        int start = (int)(ln * frac[k + 1] / 64);
        const unsigned* mr = (k & 1) ? maskB : maskA;  // built in phase k-1
        unsigned*       mw = (k & 1) ? maskA : maskB;  // for phase k+1

        // ---- project this chunk ----
        for (int i = start + tid; i < end; i += nth) {
            float px = pos[3 * i + 0];
            float py = pos[3 * i + 1];
            float pz = pos[3 * i + 2];

            float x = r00 * px + r01 * py + r02 * pz + t0;
            float y = r10 * px + r11 * py + r12 * pz + t1;
            float z = r20 * px + r21 * py + r22 * pz + t2;

            float u = fx * x / z + cx;
            float v = fy * y / z + cy;

            int xi = (int)u;   // trunc toward zero == numpy astype(int32)
            int yi = (int)v;

            if (xi >= 0 && xi < W && yi >= 0 && yi < H) {
                int pix = yi * W + xi;
                if (k > 0 && ((mr[pix >> 5] >> (pix & 31)) & 1u)) continue;
                atomicMax(&winner[pix], i);
            }
        }

        // ---- build next mask: bit p = (winner[p] >= start) ----
        if (k < NP - 1) {
            for (int p0 = tid; p0 < HW; p0 += nth) {
                bool covered = winner[p0] >= start;
                unsigned long long b = __ballot(covered);
                if ((threadIdx.x & 63) == 0) {
                    int base = p0 >> 5;        // lane0's p0 is 64-aligned
                    mw[base]     = (unsigned)b;
                    mw[base + 1] = (unsigned)(b >> 32);
                }
            }
        }

        __threadfence();   // release dirty mask lines + clean own L2
        grid.sync();
    }

    // ---- paint ----
    for (int p = tid; p < HW; p += nth) {
        int w = winner[p];
        float r = 0.0f, g = 0.0f, b = 0.0f;
        if (w >= 0) {
            r = colors[3 * w + 0];
            g = colors[3 * w + 1];
            b = colors[3 * w + 2];
            r = fminf(fmaxf(r, 0.0f), 1.0f);
            g = fminf(fmaxf(g, 0.0f), 1.0f);
            b = fminf(fmaxf(b, 0.0f), 1.0f);
        }
        out[p] = r;
        out[HW + p] = g;
        out[2 * HW + p] = b;
    }
}

// ---- fallback (no coop / small ws): memset + 1 pass + paint ----
__global__ void proj_simple(const float* __restrict__ pos,
                            const float* __restrict__ pose,
                            const float* __restrict__ intr,
                            const int* __restrict__ Hp,
                            const int* __restrict__ Wp,
                            int* __restrict__ winner, int n) {
    int i = blockIdx.x * blockDim.x + threadIdx.x;
    if (i >= n) return;
    float px = pos[3 * i], py = pos[3 * i + 1], pz = pos[3 * i + 2];
    float x = pose[0] * px + pose[1] * py + pose[2]  * pz + pose[3];
    float y = pose[4] * px + pose[5] * py + pose[6]  * pz + pose[7];
    float z = pose[8] * px + pose[9] * py + pose[10] * pz + pose[11];
    float u = intr[0] * x / z + intr[2];
    float v = intr[4] * y / z + intr[5];
    int xi = (int)u, yi = (int)v;
    int W = *Wp, H = *Hp;
    if (xi >= 0 && xi < W && yi >= 0 && yi < H) atomicMax(&winner[yi * W + xi], i);
}

__global__ void paint_simple(const int* __restrict__ winner,
                             const float* __restrict__ colors,
                             float* __restrict__ out, int HW) {
    int p = blockIdx.x * blockDim.x + threadIdx.x;
    if (p >= HW) return;
    int w = winner[p];
    float r = 0.0f, g = 0.0f, b = 0.0f;
    if (w >= 0) {
        r = fminf(fmaxf(colors[3 * w], 0.0f), 1.0f);
        g = fminf(fmaxf(colors[3 * w + 1], 0.0f), 1.0f);
        b = fminf(fmaxf(colors[3 * w + 2], 0.0f), 1.0f);
    }
    out[p] = r; out[HW + p] = g; out[2 * HW + p] = b;
}

extern "C" void kernel_launch(void* const* d_in, const int* in_sizes, int n_in,
                              void* d_out, int out_size, void* d_ws, size_t ws_size,
                              hipStream_t stream) {
    const float* positions = (const float*)d_in[0];
    const float* colors    = (const float*)d_in[1];
    const float* pose      = (const float*)d_in[2];
    const float* intr      = (const float*)d_in[3];
    const int*   Hp        = (const int*)d_in[4];
    const int*   Wp        = (const int*)d_in[5];
    float* out = (float*)d_out;

    int n  = in_sizes[0] / 3;       // number of points
    int HW = out_size / 3;          // H*W pixels

    int* winner = (int*)d_ws;
    int maskWords = HW / 32;
    unsigned* maskA = (unsigned*)(winner + HW);
    unsigned* maskB = maskA + maskWords;
    size_t need = (size_t)HW * sizeof(int) + 2ull * maskWords * sizeof(unsigned);

    if (ws_size < need || n < 4096 || (HW & 63)) {
        hipMemsetAsync(winner, 0xFF, (size_t)HW * sizeof(int), stream);
        int grid = (n + BLOCK - 1) / BLOCK;
        proj_simple<<<grid, BLOCK, 0, stream>>>(positions, pose, intr, Hp, Wp,
                                                winner, n);
        int grid2 = (HW + BLOCK - 1) / BLOCK;
        paint_simple<<<grid2, BLOCK, 0, stream>>>(winner, colors, out, HW);
        return;
    }

    // Fill winner = -1 (separate dispatch: its plain stores are flushed
    // before the coop kernel's memory-side atomics touch the same lines).
    int n4 = HW / 4;
    int fgrid = min((n4 + BLOCK - 1) / BLOCK, 2048);
    fill_ff_kernel<<<fgrid, BLOCK, 0, stream>>>((uint4*)winner, n4);

    void* args[] = {
        (void*)&positions, (void*)&colors, (void*)&pose, (void*)&intr,
        (void*)&Hp, (void*)&Wp, (void*)&winner, (void*)&maskA, (void*)&maskB,
        (void*)&out, (void*)&n, (void*)&HW
    };
    hipLaunchCooperativeKernel((const void*)fused_kernel,
                               dim3(COOP_BLOCKS), dim3(BLOCK),
                               args, 0, stream);
}

// Round 10
// 95.446 us; speedup vs baseline: 19.3776x; 19.3776x over previous
//
#include <hip/hip_runtime.h>

// Point-splat renderer, round 10: EXACT round-4 structure (best measured:
// 97.6 us total, of which ~39 us was hipMemsetAsync = SDMA blit at 107 GB/s)
// with ONE controlled change: the memset is replaced by a 2 us shader fill.
//
//  - winner[pix] = max point index via memory-side atomicMax (~26 G/s).
//  - 5 descending chunks {n/8,n/8,n/8,n/8,n/2}; between chunks a 128 KB
//    coverage bitmask (bit p = winner[p]>=0) rebuilt by a DEDICATED 4096-block
//    dispatch (read-only during proj passes -> L1/L2 resident).
//  - proj passes: one point per thread, no grid-stride (R4 config).
//
// Single-variable experiment vs R4 (fill) and vs R6 (schedule/dispatches):
// predicted ~58-65 us if R4's decomposition was right.
//
// Inputs: d_in[0] positions (N*3 f32), d_in[1] colors (N*3 f32),
//         d_in[2] camera_pose (16 f32), d_in[3] intrinsics (9 f32),
//         d_in[4] H (1 int), d_in[5] W (1 int)
// Output: (1,3,H,W) f32 flat.

__global__ void fill_ff_kernel(uint4* __restrict__ p, int n4) {
    int i = blockIdx.x * blockDim.x + threadIdx.x;
    uint4 v = make_uint4(~0u, ~0u, ~0u, ~0u);
    for (; i < n4; i += gridDim.x * blockDim.x) p[i] = v;
}

__global__ void proj_kernel(const float* __restrict__ pos,
                            const float* __restrict__ pose,
                            const float* __restrict__ intr,
                            const int* __restrict__ Hp,
                            const int* __restrict__ Wp,
                            int* __restrict__ winner,
                            const unsigned* __restrict__ mask,
                            int use_mask, int start, int end) {
    int i = start + blockIdx.x * blockDim.x + threadIdx.x;
    if (i >= end) return;

    float px = pos[3 * i + 0];
    float py = pos[3 * i + 1];
    float pz = pos[3 * i + 2];

    // pc = R * p + t
    float x = pose[0] * px + pose[1] * py + pose[2]  * pz + pose[3];
    float y = pose[4] * px + pose[5] * py + pose[6]  * pz + pose[7];
    float z = pose[8] * px + pose[9] * py + pose[10] * pz + pose[11];

    float fx = intr[0], cx = intr[2];
    float fy = intr[4], cy = intr[5];

    float u = fx * x / z + cx;
    float v = fy * y / z + cy;

    int xi = (int)u;   // trunc toward zero == numpy astype(int32)
    int yi = (int)v;

    int W = *Wp, H = *Hp;
    if (xi >= 0 && xi < W && yi >= 0 && yi < H) {
        int pix = yi * W + xi;
        if (use_mask && ((mask[pix >> 5] >> (pix & 31)) & 1u)) return; // settled
        atomicMax(&winner[pix], i);
    }
}

// coverage bitmask: bit p = (winner[p] >= 0). Fully overwrites every word.
__global__ void mask_kernel(const int* __restrict__ winner,
                            unsigned* __restrict__ mask,
                            int HW, int maskWords) {
    int p = blockIdx.x * blockDim.x + threadIdx.x;
    bool pred = (p < HW) && (winner[p] >= 0);
    unsigned long long b = __ballot(pred);
    int lane = threadIdx.x & 63;
    if (lane == 0) {
        int base = (blockIdx.x * blockDim.x + (threadIdx.x & ~63)) >> 5;
        if (base < maskWords)     mask[base]     = (unsigned)b;
        if (base + 1 < maskWords) mask[base + 1] = (unsigned)(b >> 32);
    }
}

__global__ void paint_kernel(const int* __restrict__ winner,
                             const float* __restrict__ colors,
                             float* __restrict__ out,
                             int HW) {
    int p = blockIdx.x * blockDim.x + threadIdx.x;
    if (p >= HW) return;

    int w = winner[p];
    float r = 0.0f, g = 0.0f, b = 0.0f;
    if (w >= 0) {
        r = colors[3 * w + 0];
        g = colors[3 * w + 1];
        b = colors[3 * w + 2];
        r = fminf(fmaxf(r, 0.0f), 1.0f);
        g = fminf(fmaxf(g, 0.0f), 1.0f);
        b = fminf(fmaxf(b, 0.0f), 1.0f);
    }
    out[p] = r;
    out[HW + p] = g;
    out[2 * HW + p] = b;
}

extern "C" void kernel_launch(void* const* d_in, const int* in_sizes, int n_in,
                              void* d_out, int out_size, void* d_ws, size_t ws_size,
                              hipStream_t stream) {
    const float* positions = (const float*)d_in[0];
    const float* colors    = (const float*)d_in[1];
    const float* pose      = (const float*)d_in[2];
    const float* intr      = (const float*)d_in[3];
    const int*   Hp        = (const int*)d_in[4];
    const int*   Wp        = (const int*)d_in[5];
    float* out = (float*)d_out;

    int n  = in_sizes[0] / 3;       // number of points
    int HW = out_size / 3;          // H*W pixels

    int* winner = (int*)d_ws;
    int maskWords = (HW + 31) / 32;
    unsigned* mask = (unsigned*)(winner + HW);
    size_t need = (size_t)HW * sizeof(int) + (size_t)maskWords * sizeof(unsigned);

    const int block = 256;

    if (ws_size < need || n < 4096 || (HW & 15)) {
        // Fallback: memset winner, single full atomic pass, no mask.
        hipMemsetAsync(winner, 0xFF, (size_t)HW * sizeof(int), stream);
        int grid = (n + block - 1) / block;
        proj_kernel<<<grid, block, 0, stream>>>(positions, pose, intr, Hp, Wp,
                                                winner, (const unsigned*)0, 0,
                                                0, n);
    } else {
        // winner = -1 via shader fill (the ONLY change vs round 4's 39 us
        // hipMemsetAsync/SDMA path). Mask needs no init: fully rebuilt.
        int n4 = HW / 4;
        int fgrid = min((n4 + block - 1) / block, 2048);
        fill_ff_kernel<<<fgrid, block, 0, stream>>>((uint4*)winner, n4);

        // R4 chunk schedule: n/8, n/8, n/8, n/8, n/2 (descending).
        long long ln = n;
        int bounds[6];
        bounds[0] = n;
        bounds[1] = (int)(ln * 7 / 8);
        bounds[2] = (int)(ln * 3 / 4);
        bounds[3] = (int)(ln * 5 / 8);
        bounds[4] = (int)(ln / 2);
        bounds[5] = 0;

        int maskGrid = (HW + block - 1) / block;
        for (int k = 0; k < 5; ++k) {
            int end = bounds[k], start = bounds[k + 1];
            int cnt = end - start;
            if (cnt <= 0) continue;
            int grid = (cnt + block - 1) / block;
            proj_kernel<<<grid, block, 0, stream>>>(positions, pose, intr, Hp, Wp,
                                                    winner, mask, (k > 0) ? 1 : 0,
                                                    start, end);
            if (k < 4) {
                mask_kernel<<<maskGrid, block, 0, stream>>>(winner, mask, HW,
                                                            maskWords);
            }
        }
    }

    int grid2 = (HW + block - 1) / block;
    paint_kernel<<<grid2, block, 0, stream>>>(winner, colors, out, HW);
}

// Round 11
// 78.687 us; speedup vs baseline: 23.5046x; 1.2130x over previous
//
#include <hip/hip_runtime.h>

// Point-splat renderer, round 11: LDS-tile binning, ZERO global atomics.
//
// Measured context: memory-side atomicMax is ~26 G/s (R1), winner lines never
// cache in L2 (R2), 32B is the L2 writeback sector granule (all WRITE_SIZE
// quantization). The mask/chunk family floors at ~80 us; this pipeline
// replaces it with 5 dispatches and only LDS atomics:
//   1. hist:    project 4M points once -> pixArr[i] (u32, coalesced 16 MB) +
//               per-block LDS histogram over 1024 tiles (32x32 px each);
//               histG written transposed for the scan.
//   2. prefixA: per-tile exclusive scan over the 256 blocks' padded counts
//               (segments padded to 8 entries = 32 B so no two blocks share
//               a writeback SECTOR -> no cross-XCD lost updates, the R5 bug).
//   3. prefixB: exclusive scan of per-tile totals -> tileBase.
//   4. scatter: read pixArr (consistent with hist BY CONSTRUCTION), LDS
//               cursors (ds_add returns slot), plain dense stores of packed
//               (localpix<<22 | idx); sentinel-fill the pad slots.
//   5. tilemax_paint: block per tile, ds_max(idx+1) into LDS winner[1024],
//               gather colors, write CHW output. (paint fused.)
//
// winner = max index is order-free -> deterministic despite racy slot order.
// Fallback (gates fail): round-10 mask/chunk path, known-good at 95 us.
//
// Inputs: d_in[0] positions (N*3 f32), d_in[1] colors (N*3 f32),
//         d_in[2] camera_pose (16 f32), d_in[3] intrinsics (9 f32),
//         d_in[4] H (1 int), d_in[5] W (1 int)
// Output: (1,3,H,W) f32 flat.

#define NB   256          // hist/scatter blocks
#define TB   512          // threads for hist/scatter
#define NT   1024         // tiles = 32x32 grid of 32x32-px tiles
#define IMGW 1024
#define IMGHW (1024 * 1024)

__device__ __forceinline__ unsigned align8(unsigned x) { return (x + 7u) & ~7u; }

// ---------- fast path ----------

__global__ void __launch_bounds__(TB)
hist_kernel(const float* __restrict__ pos,
            const float* __restrict__ pose,
            const float* __restrict__ intr,
            unsigned* __restrict__ pixArr,
            unsigned* __restrict__ histG,
            int n, int ppb) {
    __shared__ unsigned h[NT];
    for (int t = threadIdx.x; t < NT; t += TB) h[t] = 0;
    __syncthreads();

    float r00 = pose[0], r01 = pose[1], r02 = pose[2],  t0 = pose[3];
    float r10 = pose[4], r11 = pose[5], r12 = pose[6],  t1 = pose[7];
    float r20 = pose[8], r21 = pose[9], r22 = pose[10], t2 = pose[11];
    float fx = intr[0], cx = intr[2];
    float fy = intr[4], cy = intr[5];

    int start = blockIdx.x * ppb;
    int end = min(start + ppb, n);
    for (int i = start + threadIdx.x; i < end; i += TB) {
        float px = pos[3 * i + 0];
        float py = pos[3 * i + 1];
        float pz = pos[3 * i + 2];
        float x = r00 * px + r01 * py + r02 * pz + t0;
        float y = r10 * px + r11 * py + r12 * pz + t1;
        float z = r20 * px + r21 * py + r22 * pz + t2;
        float u = fx * x / z + cx;
        float v = fy * y / z + cy;
        int xi = (int)u;   // trunc toward zero == numpy astype(int32)
        int yi = (int)v;
        unsigned pv = 0xFFFFFFFFu;
        if (xi >= 0 && xi < IMGW && yi >= 0 && yi < IMGW) {
            pv = ((unsigned)yi << 10) | (unsigned)xi;
            int t = ((yi >> 5) << 5) + (xi >> 5);
            atomicAdd(&h[t], 1u);              // LDS
        }
        pixArr[i] = pv;
    }
    __syncthreads();
    for (int t = threadIdx.x; t < NT; t += TB)
        histG[t * NB + blockIdx.x] = h[t];     // transposed for prefixA
}

__global__ void __launch_bounds__(NB)
prefixA_kernel(const unsigned* __restrict__ histG,
               unsigned* __restrict__ baseT,
               unsigned* __restrict__ tilePad) {
    __shared__ unsigned s[NB];
    int t = blockIdx.x;
    int b = threadIdx.x;
    unsigned padded = align8(histG[t * NB + b]);
    s[b] = padded;
    __syncthreads();
    unsigned v = padded;
    for (int off = 1; off < NB; off <<= 1) {
        unsigned add = (b >= off) ? s[b - off] : 0u;
        __syncthreads();
        v += add;
        s[b] = v;
        __syncthreads();
    }
    baseT[t * NB + b] = v - padded;            // exclusive prefix (padded)
    if (b == NB - 1) tilePad[t] = v;           // padded total for tile t
}

__global__ void __launch_bounds__(NT)
prefixB_kernel(const unsigned* __restrict__ tilePad,
               unsigned* __restrict__ tileBase) {
    __shared__ unsigned s[NT];
    int t = threadIdx.x;
    unsigned x = tilePad[t];
    s[t] = x;
    __syncthreads();
    unsigned v = x;
    for (int off = 1; off < NT; off <<= 1) {
        unsigned add = (t >= off) ? s[t - off] : 0u;
        __syncthreads();
        v += add;
        s[t] = v;
        __syncthreads();
    }
    tileBase[t] = v - x;
    if (t == NT - 1) tileBase[NT] = v;
}

__global__ void __launch_bounds__(TB)
scatter_kernel(const unsigned* __restrict__ pixArr,
               const unsigned* __restrict__ baseT,
               const unsigned* __restrict__ tileBase,
               unsigned* __restrict__ bins,
               int n, int ppb) {
    __shared__ unsigned cursor[NT];
    __shared__ unsigned seg0[NT];
    int b = blockIdx.x;
    for (int t = threadIdx.x; t < NT; t += TB) {
        unsigned s0 = tileBase[t] + baseT[t * NB + b];
        seg0[t] = s0;
        cursor[t] = s0;
    }
    __syncthreads();

    int start = b * ppb;
    int end = min(start + ppb, n);
    for (int i = start + threadIdx.x; i < end; i += TB) {
        unsigned pv = pixArr[i];
        if (pv == 0xFFFFFFFFu) continue;
        unsigned xi = pv & 1023u, yi = pv >> 10;
        unsigned t  = ((yi >> 5) << 5) + (xi >> 5);
        unsigned lp = ((yi & 31u) << 5) + (xi & 31u);
        unsigned slot = atomicAdd(&cursor[t], 1u);     // LDS: slot rank
        bins[slot] = (lp << 22) | (unsigned)i;
    }
    __syncthreads();
    // sentinel-fill pad slots (segment is 8-entry aligned by prefixA)
    for (int t = threadIdx.x; t < NT; t += TB) {
        unsigned cur = cursor[t], s0 = seg0[t];
        unsigned segEnd = s0 + align8(cur - s0);
        for (unsigned s = cur; s < segEnd; ++s) bins[s] = 0xFFFFFFFFu;
    }
}

__global__ void __launch_bounds__(256)
tilemax_paint_kernel(const unsigned* __restrict__ bins,
                     const unsigned* __restrict__ tileBase,
                     const float* __restrict__ colors,
                     float* __restrict__ out,
                     int n) {
    __shared__ unsigned win[NT];   // winner index + 1 per local pixel
    int t = blockIdx.x;
    for (int l = threadIdx.x; l < NT; l += 256) win[l] = 0;
    __syncthreads();

    unsigned s0 = tileBase[t], s1 = tileBase[t + 1];
    for (unsigned s = s0 + threadIdx.x; s < s1; s += 256) {
        unsigned e = bins[s];
        unsigned idx = e & 0x3FFFFFu;
        if (idx < (unsigned)n) atomicMax(&win[e >> 22], idx + 1u);  // LDS
    }
    __syncthreads();

    int tx = (t & 31) << 5, ty = (t >> 5) << 5;
    for (int l = threadIdx.x; l < NT; l += 256) {
        unsigned w = win[l];
        float r = 0.0f, g = 0.0f, bl = 0.0f;
        if (w) {
            unsigned wi = w - 1u;
            r  = fminf(fmaxf(colors[3 * wi + 0], 0.0f), 1.0f);
            g  = fminf(fmaxf(colors[3 * wi + 1], 0.0f), 1.0f);
            bl = fminf(fmaxf(colors[3 * wi + 2], 0.0f), 1.0f);
        }
        int x = tx + (l & 31), y = ty + (l >> 5);
        int p = y * IMGW + x;
        out[p] = r;
        out[IMGHW + p] = g;
        out[2 * IMGHW + p] = bl;
    }
}

// ---------- fallback: round-10 mask/chunk path (known-good, ~95 us) ----------

__global__ void fill_ff_kernel(uint4* __restrict__ p, int n4) {
    int i = blockIdx.x * blockDim.x + threadIdx.x;
    uint4 v = make_uint4(~0u, ~0u, ~0u, ~0u);
    for (; i < n4; i += gridDim.x * blockDim.x) p[i] = v;
}

__global__ void proj_kernel(const float* __restrict__ pos,
                            const float* __restrict__ pose,
                            const float* __restrict__ intr,
                            const int* __restrict__ Hp,
                            const int* __restrict__ Wp,
                            int* __restrict__ winner,
                            const unsigned* __restrict__ mask,
                            int use_mask, int start, int end) {
    int i = start + blockIdx.x * blockDim.x + threadIdx.x;
    if (i >= end) return;
    float px = pos[3 * i], py = pos[3 * i + 1], pz = pos[3 * i + 2];
    float x = pose[0] * px + pose[1] * py + pose[2]  * pz + pose[3];
    float y = pose[4] * px + pose[5] * py + pose[6]  * pz + pose[7];
    float z = pose[8] * px + pose[9] * py + pose[10] * pz + pose[11];
    float u = intr[0] * x / z + intr[2];
    float v = intr[4] * y / z + intr[5];
    int xi = (int)u, yi = (int)v;
    int W = *Wp, H = *Hp;
    if (xi >= 0 && xi < W && yi >= 0 && yi < H) {
        int pix = yi * W + xi;
        if (use_mask && ((mask[pix >> 5] >> (pix & 31)) & 1u)) return;
        atomicMax(&winner[pix], i);
    }
}

__global__ void mask_kernel(const int* __restrict__ winner,
                            unsigned* __restrict__ mask,
                            int HW, int maskWords) {
    int p = blockIdx.x * blockDim.x + threadIdx.x;
    bool pred = (p < HW) && (winner[p] >= 0);
    unsigned long long b = __ballot(pred);
    if ((threadIdx.x & 63) == 0) {
        int base = (blockIdx.x * blockDim.x + (threadIdx.x & ~63)) >> 5;
        if (base < maskWords)     mask[base]     = (unsigned)b;
        if (base + 1 < maskWords) mask[base + 1] = (unsigned)(b >> 32);
    }
}

__global__ void paint_kernel(const int* __restrict__ winner,
                             const float* __restrict__ colors,
                             float* __restrict__ out, int HW) {
    int p = blockIdx.x * blockDim.x + threadIdx.x;
    if (p >= HW) return;
    int w = winner[p];
    float r = 0.0f, g = 0.0f, b = 0.0f;
    if (w >= 0) {
        r = fminf(fmaxf(colors[3 * w + 0], 0.0f), 1.0f);
        g = fminf(fmaxf(colors[3 * w + 1], 0.0f), 1.0f);
        b = fminf(fmaxf(colors[3 * w + 2], 0.0f), 1.0f);
    }
    out[p] = r; out[HW + p] = g; out[2 * HW + p] = b;
}

extern "C" void kernel_launch(void* const* d_in, const int* in_sizes, int n_in,
                              void* d_out, int out_size, void* d_ws, size_t ws_size,
                              hipStream_t stream) {
    const float* positions = (const float*)d_in[0];
    const float* colors    = (const float*)d_in[1];
    const float* pose      = (const float*)d_in[2];
    const float* intr      = (const float*)d_in[3];
    const int*   Hp        = (const int*)d_in[4];
    const int*   Wp        = (const int*)d_in[5];
    float* out = (float*)d_out;

    int n  = in_sizes[0] / 3;       // number of points
    int HW = out_size / 3;          // H*W pixels

    // ---- fast-path workspace carve ----
    size_t binsCap = (size_t)n + (size_t)NB * NT * 7 + 8;   // worst-case pad
    unsigned* bins     = (unsigned*)d_ws;
    unsigned* pixArr   = bins + binsCap;
    unsigned* histG    = pixArr + n;
    unsigned* baseT    = histG + (size_t)NT * NB;
    unsigned* tilePad  = baseT + (size_t)NT * NB;
    unsigned* tileBase = tilePad + NT;
    size_t needFast = (size_t)((tileBase + NT + 1) - bins) * sizeof(unsigned);

    bool fast = (HW == IMGHW) && (n >= 4096) && (n < 4100000) &&
                (ws_size >= needFast);

    if (fast) {
        int ppb = (n + NB - 1) / NB;
        hist_kernel<<<NB, TB, 0, stream>>>(positions, pose, intr,
                                           pixArr, histG, n, ppb);
        prefixA_kernel<<<NT, NB, 0, stream>>>(histG, baseT, tilePad);
        prefixB_kernel<<<1, NT, 0, stream>>>(tilePad, tileBase);
        scatter_kernel<<<NB, TB, 0, stream>>>(pixArr, baseT, tileBase,
                                              bins, n, ppb);
        tilemax_paint_kernel<<<NT, 256, 0, stream>>>(bins, tileBase,
                                                     colors, out, n);
        return;
    }

    // ---- fallback: round-10 structure ----
    int* winner = (int*)d_ws;
    int maskWords = (HW + 31) / 32;
    unsigned* mask = (unsigned*)(winner + HW);
    size_t need = (size_t)HW * sizeof(int) + (size_t)maskWords * 4;
    const int block = 256;

    if (ws_size < need || n < 4096 || (HW & 15)) {
        hipMemsetAsync(winner, 0xFF, (size_t)HW * sizeof(int), stream);
        int grid = (n + block - 1) / block;
        proj_kernel<<<grid, block, 0, stream>>>(positions, pose, intr, Hp, Wp,
                                                winner, (const unsigned*)0, 0,
                                                0, n);
    } else {
        int n4 = HW / 4;
        int fgrid = min((n4 + block - 1) / block, 2048);
        fill_ff_kernel<<<fgrid, block, 0, stream>>>((uint4*)winner, n4);
        long long ln = n;
        int bounds[6];
        bounds[0] = n;
        bounds[1] = (int)(ln * 7 / 8);
        bounds[2] = (int)(ln * 3 / 4);
        bounds[3] = (int)(ln * 5 / 8);
        bounds[4] = (int)(ln / 2);
        bounds[5] = 0;
        int maskGrid = (HW + block - 1) / block;
        for (int k = 0; k < 5; ++k) {
            int end = bounds[k], start = bounds[k + 1];
            if (end <= start) continue;
            int grid = (end - start + block - 1) / block;
            proj_kernel<<<grid, block, 0, stream>>>(positions, pose, intr, Hp, Wp,
                                                    winner, mask, (k > 0) ? 1 : 0,
                                                    start, end);
            if (k < 4)
                mask_kernel<<<maskGrid, block, 0, stream>>>(winner, mask, HW,
                                                            maskWords);
        }
    }
    int grid2 = (HW + block - 1) / block;
    paint_kernel<<<grid2, block, 0, stream>>>(winner, colors, out, HW);
}

// Round 13
// 63.715 us; speedup vs baseline: 29.0278x; 1.2350x over previous
//
#include <hip/hip_runtime.h>

// Point-splat renderer, round 13 (= round 12 + host/device align8 fix):
// single-kernel block-local binning + fused tile-max/paint.
//
//  Kernel 1 (binsort, 512 blocks x 512 thr): each block owns points
//  [b*ppb, b*ppb+cnt) and a FIXED private region of bins (deterministic, no
//  global scan). In LDS: project+stash packed pixel (31 KB), 1024-tile
//  histogram, exclusive scan of 8-PADDED counts (32B-aligned sub-segments ->
//  no cross-block writeback-sector sharing), then replay stash through LDS
//  cursors and store (lp<<22|idx) densely. Writes per-(block,tile)
//  (base<<16|count) to a 2 MB table, transposed for paint.
//
//  Kernel 2 (paint, 1024 tile-blocks x 512 thr): thread b walks the exact
//  count of sub-segment (b, tile) (pads never read), LDS atomicMax(idx+1),
//  then gathers colors for the 32x32 tile and writes CHW output.
//
//  winner = max index is order-free -> deterministic despite racy slot order;
//  region layout is fixed -> deterministic work/output.
//
// Inputs: d_in[0] positions (N*3 f32), d_in[1] colors (N*3 f32),
//         d_in[2] camera_pose (16 f32), d_in[3] intrinsics (9 f32),
//         d_in[4] H (1 int), d_in[5] W (1 int)
// Output: (1,3,H,W) f32 flat.

#define NB      512            // binsort blocks
#define TB      512            // threads per binsort/paint block
#define NT      1024           // 32x32 grid of 32x32-px tiles
#define PPB_MAX 7936           // stash capacity (LDS), points per block
#define IMGW    1024
#define IMGHW   (1024 * 1024)

__host__ __device__ __forceinline__ unsigned align8(unsigned x) {
    return (x + 7u) & ~7u;
}

__global__ void __launch_bounds__(TB)
binsort_kernel(const float* __restrict__ pos,
               const float* __restrict__ pose,
               const float* __restrict__ intr,
               unsigned* __restrict__ bins,
               unsigned* __restrict__ histG,
               int n, int ppb, int region) {
    __shared__ unsigned stash[PPB_MAX];
    __shared__ unsigned h[NT];
    __shared__ unsigned base_[NT];
    __shared__ unsigned cur[NT];
    __shared__ unsigned sc[TB];

    int tid = threadIdx.x;
    for (int t = tid; t < NT; t += TB) h[t] = 0;
    __syncthreads();

    float r00 = pose[0], r01 = pose[1], r02 = pose[2],  t0 = pose[3];
    float r10 = pose[4], r11 = pose[5], r12 = pose[6],  t1 = pose[7];
    float r20 = pose[8], r21 = pose[9], r22 = pose[10], t2 = pose[11];
    float fx = intr[0], cx = intr[2];
    float fy = intr[4], cy = intr[5];

    int start = blockIdx.x * ppb;
    int cnt = min(start + ppb, n) - start;
    if (cnt < 0) cnt = 0;

    // ---- pass 1: project, stash packed pixel in LDS, LDS histogram ----
    for (int j = tid; j < cnt; j += TB) {
        int i = start + j;
        float px = pos[3 * i + 0];
        float py = pos[3 * i + 1];
        float pz = pos[3 * i + 2];
        float x = r00 * px + r01 * py + r02 * pz + t0;
        float y = r10 * px + r11 * py + r12 * pz + t1;
        float z = r20 * px + r21 * py + r22 * pz + t2;
        float u = fx * x / z + cx;
        float v = fy * y / z + cy;
        int xi = (int)u;   // trunc toward zero == numpy astype(int32)
        int yi = (int)v;
        unsigned pv = 0xFFFFFFFFu;
        if (xi >= 0 && xi < IMGW && yi >= 0 && yi < IMGW) {
            pv = ((unsigned)yi << 10) | (unsigned)xi;
            int t = ((yi >> 5) << 5) + (xi >> 5);
            atomicAdd(&h[t], 1u);                       // LDS
        }
        stash[j] = pv;
    }
    __syncthreads();

    // ---- exclusive scan of 8-padded counts (thread owns tiles 2t,2t+1) ----
    unsigned a0 = align8(h[2 * tid]);
    unsigned a1 = align8(h[2 * tid + 1]);
    unsigned v = a0 + a1;
    sc[tid] = v;
    __syncthreads();
    for (int off = 1; off < TB; off <<= 1) {
        unsigned add = (tid >= off) ? sc[tid - off] : 0u;
        __syncthreads();
        v += add;
        sc[tid] = v;
        __syncthreads();
    }
    base_[2 * tid]     = v - a0 - a1;
    base_[2 * tid + 1] = v - a1;
    __syncthreads();

    // ---- publish (base<<16 | count) transposed; init cursors ----
    for (int t = tid; t < NT; t += TB) {
        cur[t] = base_[t];
        histG[(size_t)t * NB + blockIdx.x] = (base_[t] << 16) | h[t];
    }
    __syncthreads();

    // ---- pass 2: replay stash -> dense stores into private region ----
    unsigned* myRegion = bins + (size_t)blockIdx.x * (size_t)region;
    for (int j = tid; j < cnt; j += TB) {
        unsigned pv = stash[j];
        if (pv == 0xFFFFFFFFu) continue;
        unsigned xi = pv & 1023u, yi = pv >> 10;
        unsigned t  = ((yi >> 5) << 5) + (xi >> 5);
        unsigned lp = ((yi & 31u) << 5) + (xi & 31u);
        unsigned slot = atomicAdd(&cur[t], 1u);         // LDS
        myRegion[slot] = (lp << 22) | (unsigned)(start + j);
    }
}

__global__ void __launch_bounds__(TB)
paint_kernel(const unsigned* __restrict__ bins,
             const unsigned* __restrict__ histG,
             const float* __restrict__ colors,
             float* __restrict__ out,
             int region) {
    __shared__ unsigned win[NT];    // winner index + 1 per local pixel
    int t = blockIdx.x;
    int tid = threadIdx.x;
    for (int l = tid; l < NT; l += TB) win[l] = 0;
    __syncthreads();

    // thread b owns sub-segment (block b, tile t): exact count, pads unread
    unsigned pk = histG[(size_t)t * NB + tid];
    unsigned sbase = pk >> 16, cnt = pk & 0xFFFFu;
    const unsigned* seg = bins + (size_t)tid * (size_t)region + sbase;
    for (unsigned k = 0; k < cnt; ++k) {
        unsigned e = seg[k];
        atomicMax(&win[e >> 22], (e & 0x3FFFFFu) + 1u); // LDS
    }
    __syncthreads();

    int tx = (t & 31) << 5, ty = (t >> 5) << 5;
    for (int l = tid; l < NT; l += TB) {
        unsigned w = win[l];
        float r = 0.0f, g = 0.0f, bl = 0.0f;
        if (w) {
            unsigned wi = w - 1u;
            r  = fminf(fmaxf(colors[3 * wi + 0], 0.0f), 1.0f);
            g  = fminf(fmaxf(colors[3 * wi + 1], 0.0f), 1.0f);
            bl = fminf(fmaxf(colors[3 * wi + 2], 0.0f), 1.0f);
        }
        int x = tx + (l & 31), y = ty + (l >> 5);
        int p = y * IMGW + x;
        out[p] = r;
        out[IMGHW + p] = g;
        out[2 * IMGHW + p] = bl;
    }
}

// ---------- fallback: memset + single atomic pass + paint ----------

__global__ void proj_simple(const float* __restrict__ pos,
                            const float* __restrict__ pose,
                            const float* __restrict__ intr,
                            const int* __restrict__ Hp,
                            const int* __restrict__ Wp,
                            int* __restrict__ winner, int n) {
    int i = blockIdx.x * blockDim.x + threadIdx.x;
    if (i >= n) return;
    float px = pos[3 * i], py = pos[3 * i + 1], pz = pos[3 * i + 2];
    float x = pose[0] * px + pose[1] * py + pose[2]  * pz + pose[3];
    float y = pose[4] * px + pose[5] * py + pose[6]  * pz + pose[7];
    float z = pose[8] * px + pose[9] * py + pose[10] * pz + pose[11];
    float u = intr[0] * x / z + intr[2];
    float v = intr[4] * y / z + intr[5];
    int xi = (int)u, yi = (int)v;
    int W = *Wp, H = *Hp;
    if (xi >= 0 && xi < W && yi >= 0 && yi < H) atomicMax(&winner[yi * W + xi], i);
}

__global__ void paint_simple(const int* __restrict__ winner,
                             const float* __restrict__ colors,
                             float* __restrict__ out, int HW) {
    int p = blockIdx.x * blockDim.x + threadIdx.x;
    if (p >= HW) return;
    int w = winner[p];
    float r = 0.0f, g = 0.0f, b = 0.0f;
    if (w >= 0) {
        r = fminf(fmaxf(colors[3 * w + 0], 0.0f), 1.0f);
        g = fminf(fmaxf(colors[3 * w + 1], 0.0f), 1.0f);
        b = fminf(fmaxf(colors[3 * w + 2], 0.0f), 1.0f);
    }
    out[p] = r; out[HW + p] = g; out[2 * HW + p] = b;
}

extern "C" void kernel_launch(void* const* d_in, const int* in_sizes, int n_in,
                              void* d_out, int out_size, void* d_ws, size_t ws_size,
                              hipStream_t stream) {
    const float* positions = (const float*)d_in[0];
    const float* colors    = (const float*)d_in[1];
    const float* pose      = (const float*)d_in[2];
    const float* intr      = (const float*)d_in[3];
    const int*   Hp        = (const int*)d_in[4];
    const int*   Wp        = (const int*)d_in[5];
    float* out = (float*)d_out;

    int n  = in_sizes[0] / 3;       // number of points
    int HW = out_size / 3;          // H*W pixels

    int ppb = (n + NB - 1) / NB;
    int region = (int)align8((unsigned)ppb) + 7 * NT;   // padded worst case
    unsigned* bins  = (unsigned*)d_ws;
    unsigned* histG = bins + (size_t)NB * (size_t)region;
    size_t needFast = ((size_t)NB * region + (size_t)NT * NB) * sizeof(unsigned);

    bool fast = (HW == IMGHW) && (n >= 4096) && (ppb <= PPB_MAX) &&
                (n <= 4000000) && (ws_size >= needFast);

    if (fast) {
        binsort_kernel<<<NB, TB, 0, stream>>>(positions, pose, intr,
                                              bins, histG, n, ppb, region);
        paint_kernel<<<NT, TB, 0, stream>>>(bins, histG, colors, out, region);
        return;
    }

    // ---- fallback ----
    int* winner = (int*)d_ws;
    const int block = 256;
    hipMemsetAsync(winner, 0xFF, (size_t)HW * sizeof(int), stream);
    int grid = (n + block - 1) / block;
    proj_simple<<<grid, block, 0, stream>>>(positions, pose, intr, Hp, Wp,
                                            winner, n);
    int grid2 = (HW + block - 1) / block;
    paint_simple<<<grid2, block, 0, stream>>>(winner, colors, out, HW);
}